// Round 1
// baseline (45594.339 us; speedup 1.0000x reference)
//
#include <hip/hip_runtime.h>

#define NB 64
#define NS 512
#define NI 64
#define NE 256
#define ND 256
#define N4E 1024
#define N4D 1024
#define NTE 512   // 2*E

__device__ __forceinline__ float fsig(float x){
    return __fdividef(1.f, 1.f + __expf(-x));
}
__device__ __forceinline__ float ftanh(float x){
    x = fminf(10.f, fmaxf(-10.f, x));
    float e = __expf(2.f*x);
    return 1.f - __fdividef(2.f, e + 1.f);
}
__device__ __forceinline__ float wave_sum(float v){
    #pragma unroll
    for (int o=32;o>0;o>>=1) v += __shfl_xor(v, o, 64);
    return v;
}
__device__ __forceinline__ float wave_max(float v){
    #pragma unroll
    for (int o=32;o>0;o>>=1) v = fmaxf(v, __shfl_xor(v, o, 64));
    return v;
}

// dst[C][R] = src[R][C-slice]: dst[c*R + r] = src[r*ld + off + c]
__global__ void k_transpose(float* __restrict__ dst, const float* __restrict__ src,
                            int R, int C, int ld, int off){
    int idx = blockIdx.x*256 + threadIdx.x;
    if (idx >= R*C) return;
    int r = idx / C, c = idx - r*C;
    dst[(size_t)c*R + r] = src[(size_t)r*ld + off + c];
}

__global__ void k_pack_wy(float* __restrict__ wy, const float* __restrict__ Wih_d){
    int j = blockIdx.x*256 + threadIdx.x;
    if (j < N4D) wy[j] = Wih_d[(size_t)j*(NTE+1)];
}

// zc[b][j] = b_d[j] + sum_d h0d[b][d] * Whh_d[j][d]   (WhhTd is [d][j])
__global__ void k_zc(float* __restrict__ zc, const float* __restrict__ WhhTd,
                     const float* __restrict__ h0d, const float* __restrict__ b_d){
    int b = blockIdx.x, tid = threadIdx.x;
    __shared__ float h0[ND];
    if (tid < ND) h0[tid] = h0d[b*ND + tid];
    __syncthreads();
    for (int j = tid; j < N4D; j += 256){
        float acc = b_d[j];
        #pragma unroll 8
        for (int d=0; d<ND; ++d) acc = fmaf(h0[d], WhhTd[d*N4D + j], acc);
        zc[b*N4D + j] = acc;
    }
}

// Persistent bidirectional encoder: one block per (dir, batch), 512 threads,
// each thread owns j = 2*tid, 2*tid+1 of the 4E gate pre-activations.
__global__ __launch_bounds__(512) void k_enc(
    const float* __restrict__ x, const float* __restrict__ eh0, const float* __restrict__ ec0,
    const float* __restrict__ WihTf, const float* __restrict__ WhhTf, const float* __restrict__ bf,
    const float* __restrict__ WihTb, const float* __restrict__ WhhTb, const float* __restrict__ bb,
    float* __restrict__ enc_out)
{
    int bid = blockIdx.x;
    int dir = bid & 1, b = bid >> 1;
    const float2* Wih2 = (const float2*)(dir ? WihTb : WihTf);  // [i][j] as float2 over j
    const float2* Whh2 = (const float2*)(dir ? WhhTb : WhhTf);  // [d][j]
    const float*  bias = dir ? bb : bf;
    int tid = threadIdx.x;
    __shared__ float h[NE], c[NE], xt[NI], z[N4E];
    __shared__ float2 bl[512];
    bl[tid] = ((const float2*)bias)[tid];
    if (tid < NE){
        h[tid] = eh0[(dir*NB + b)*NE + tid];
        c[tid] = ec0[(dir*NB + b)*NE + tid];
    }
    __syncthreads();
    for (int t=0; t<NS; ++t){
        int st = dir ? (NS-1-t) : t;
        if (tid < NI) xt[tid] = x[((size_t)b*NS + st)*NI + tid];
        __syncthreads();
        float2 acc = bl[tid];
        #pragma unroll 8
        for (int i=0;i<NI;++i){
            float xv = xt[i]; float2 w = Wih2[i*512 + tid];
            acc.x = fmaf(xv, w.x, acc.x); acc.y = fmaf(xv, w.y, acc.y);
        }
        #pragma unroll 8
        for (int d=0;d<NE;++d){
            float hv = h[d]; float2 w = Whh2[d*512 + tid];
            acc.x = fmaf(hv, w.x, acc.x); acc.y = fmaf(hv, w.y, acc.y);
        }
        ((float2*)z)[tid] = acc;
        __syncthreads();
        if (tid < NE){
            float zi=z[tid], zf=z[NE+tid], zg=z[2*NE+tid], zo=z[3*NE+tid];
            float cn = fsig(zf)*c[tid] + fsig(zi)*ftanh(zg);
            float hn = fsig(zo)*ftanh(cn);
            c[tid]=cn; h[tid]=hn;
            enc_out[((size_t)b*NS + st)*NTE + dir*NE + tid] = hn;
        }
        __syncthreads();
    }
}

// enc_projT[b][d][s] = b_attn[d] + sum_e enc_out[b][s][e] * W_attn[d][256+e]
// WeT is [e][d]. Block = (s-tile of 16, b), 256 threads (thread = d).
__global__ __launch_bounds__(256) void k_encproj(const float* __restrict__ enc_out,
        const float* __restrict__ WeT, const float* __restrict__ b_attn,
        float* __restrict__ enc_projT){
    int b = blockIdx.y, s0 = blockIdx.x*16, tid = threadIdx.x;
    __shared__ float tile[16*NTE];
    for (int k=0;k<32;++k){
        int li = k*256 + tid;
        tile[li] = enc_out[((size_t)b*NS + s0 + (li>>9))*NTE + (li&511)];
    }
    __syncthreads();
    float acc[16];
    float ba = b_attn[tid];
    #pragma unroll
    for (int sl=0;sl<16;++sl) acc[sl]=ba;
    for (int e=0;e<NTE;++e){
        float w = WeT[e*ND + tid];
        #pragma unroll
        for (int sl=0;sl<16;++sl) acc[sl] = fmaf(tile[sl*NTE+e], w, acc[sl]);
    }
    float4* dst = (float4*)(enc_projT + ((size_t)b*ND + tid)*NS + s0);
    #pragma unroll
    for (int q=0;q<4;++q) dst[q] = make_float4(acc[4*q],acc[4*q+1],acc[4*q+2],acc[4*q+3]);
}

// Persistent decoder: one block per batch, 1024 threads, 512 internal steps.
__global__ __launch_bounds__(1024) void k_dec(
    const float* __restrict__ enc_out, const float* __restrict__ enc_projT,
    const float* __restrict__ WhT,  // [k][d] of W_attn h-part
    const float* __restrict__ v,
    const float* __restrict__ zc, const float* __restrict__ wy,
    const float* __restrict__ WdT,  // [e][j]
    const float* __restrict__ dec_h0, const float* __restrict__ dec_c0,
    const float* __restrict__ W_lin, const float* __restrict__ b_lin,
    float* __restrict__ out)
{
    int b = blockIdx.x, tid = threadIdx.x;
    __shared__ float h_attn[ND], hproj[ND], c0[ND], v_l[ND];
    __shared__ float hp_part[4*ND];
    __shared__ float scores[NS];
    __shared__ float sc_part[2*NS];
    __shared__ float ctx_part[2*NTE];
    __shared__ float context[NTE];
    __shared__ float zbuf[N4D];
    __shared__ float zc_l[N4D], wy_l[N4D];
    __shared__ float wl_l[ND+NTE];
    __shared__ float wred[16];
    __shared__ float scal[3];   // 0: max, 1: 1/sum, 2: y

    for (int j=tid; j<N4D; j+=1024){ zc_l[j]=zc[b*N4D+j]; wy_l[j]=wy[j]; }
    if (tid < ND+NTE) wl_l[tid] = W_lin[tid];
    if (tid < ND){
        h_attn[tid] = dec_h0[b*ND + tid];
        c0[tid]     = dec_c0[b*ND + tid];
        v_l[tid]    = v[tid];
    }
    if (tid == 0) scal[2] = 0.f;
    __syncthreads();

    const float* epT = enc_projT + (size_t)b*ND*NS;  // [d][s]
    const float* eo  = enc_out  + (size_t)b*NS*NTE;  // [s][e]
    float blin = b_lin[0];

    for (int t=0; t<NS; ++t){
        // phase 1: hproj[d] = sum_k h_attn[k]*WhT[k][d], 4-way k-split
        {
            int d = tid & 255, q = tid >> 8;
            float acc = 0.f;
            #pragma unroll 8
            for (int k=q*64; k<q*64+64; ++k) acc = fmaf(h_attn[k], WhT[k*ND + d], acc);
            hp_part[q*ND + d] = acc;
        }
        __syncthreads();
        if (tid < ND) hproj[tid] = hp_part[tid]+hp_part[ND+tid]+hp_part[2*ND+tid]+hp_part[3*ND+tid];
        __syncthreads();
        // phase 2: scores[s] = sum_d v[d]*tanh(enc_projT[d][s]+hproj[d]), 2-way d-split
        {
            int s = tid & 511, half = tid >> 9;
            float acc = 0.f;
            const float* ep = epT + (size_t)(half*128)*NS + s;
            #pragma unroll 4
            for (int dd=0; dd<128; ++dd){
                int d = half*128 + dd;
                acc = fmaf(v_l[d], ftanh(ep[(size_t)dd*NS] + hproj[d]), acc);
            }
            sc_part[half*NS + s] = acc;
        }
        __syncthreads();
        // phase 3: combine + block max
        {
            float scv = (tid<NS) ? sc_part[tid]+sc_part[NS+tid] : -1e30f;
            if (tid<NS) scores[tid] = scv;
            float wm = wave_max(scv);
            if ((tid&63)==0) wred[tid>>6] = wm;
        }
        __syncthreads();
        if (tid==0){ float m=wred[0]; for(int w=1;w<8;++w) m=fmaxf(m,wred[w]); scal[0]=m; }
        __syncthreads();
        // phase 4: exp + block sum (scores[] <- unnormalized attn)
        {
            float ev = (tid<NS) ? __expf(scores[tid]-scal[0]) : 0.f;
            if (tid<NS) scores[tid] = ev;
            float wsm = wave_sum(ev);
            if ((tid&63)==0) wred[tid>>6] = wsm;
        }
        __syncthreads();
        if (tid==0){ float s=0.f; for(int w=0;w<8;++w) s+=wred[w]; scal[1]=1.f/s; }
        __syncthreads();
        // phase 5: context[e] = (1/sum) * sum_s attn[s]*enc_out[s][e], 2-way s-split
        {
            int e = tid & 511, half = tid >> 9;
            float acc = 0.f;
            const float* eop = eo + (size_t)(half*256)*NTE + e;
            #pragma unroll 4
            for (int ss=0; ss<256; ++ss) acc = fmaf(scores[half*256+ss], eop[(size_t)ss*NTE], acc);
            ctx_part[half*NTE + e] = acc;
        }
        __syncthreads();
        if (tid < NTE) context[tid] = (ctx_part[tid]+ctx_part[NTE+tid]) * scal[1];
        __syncthreads();
        // phase 6: z[j] = zc[j] + y*wy[j] + sum_e context[e]*WdT[e][j]
        {
            float acc = zc_l[tid] + scal[2]*wy_l[tid];
            #pragma unroll 8
            for (int e=0;e<NTE;++e) acc = fmaf(context[e], WdT[e*N4D + tid], acc);
            zbuf[tid] = acc;
        }
        __syncthreads();
        // phase 7: gates + output dot
        float yp = 0.f;
        if (tid < ND){
            float zi=zbuf[tid], zf=zbuf[ND+tid], zg=zbuf[2*ND+tid], zo=zbuf[3*ND+tid];
            float cn = fsig(zf)*c0[tid] + fsig(zi)*ftanh(zg);
            float hn = fsig(zo)*ftanh(cn);
            h_attn[tid] = hn;                 // consumed next step after barrier
            yp = hn * wl_l[tid];
        } else if (tid < ND+NTE){
            yp = context[tid-ND] * wl_l[tid];
        }
        {
            float wsm = wave_sum(yp);
            if ((tid&63)==0) wred[tid>>6] = wsm;
        }
        __syncthreads();
        if (tid==0){
            float yv = blin;
            for (int w=0;w<16;++w) yv += wred[w];
            out[(size_t)b*NS + t] = yv;
            scal[2] = yv;
        }
        __syncthreads();
    }
}

extern "C" void kernel_launch(void* const* d_in, const int* in_sizes, int n_in,
                              void* d_out, int out_size, void* d_ws, size_t ws_size,
                              hipStream_t stream){
    const float* x      = (const float*)d_in[0];
    const float* enc_h0 = (const float*)d_in[1];
    const float* enc_c0 = (const float*)d_in[2];
    const float* dec_h0 = (const float*)d_in[3];
    const float* dec_c0 = (const float*)d_in[4];
    const float* Wih_f  = (const float*)d_in[5];
    const float* Whh_f  = (const float*)d_in[6];
    const float* b_f    = (const float*)d_in[7];
    const float* Wih_b  = (const float*)d_in[8];
    const float* Whh_b  = (const float*)d_in[9];
    const float* b_b    = (const float*)d_in[10];
    const float* W_attn = (const float*)d_in[11];
    const float* b_attn = (const float*)d_in[12];
    const float* v      = (const float*)d_in[13];
    const float* Wih_d  = (const float*)d_in[14];
    const float* Whh_d  = (const float*)d_in[15];
    const float* b_d    = (const float*)d_in[16];
    const float* W_lin  = (const float*)d_in[17];
    const float* b_lin  = (const float*)d_in[18];
    float* out = (float*)d_out;
    float* ws  = (float*)d_ws;

    size_t o_enc_out  = 0;
    size_t o_encprojT = o_enc_out  + (size_t)NB*NS*NTE;   // 16,777,216
    size_t o_WihTf    = o_encprojT + (size_t)NB*ND*NS;    //  8,388,608
    size_t o_WhhTf    = o_WihTf + (size_t)NI*N4E;
    size_t o_WihTb    = o_WhhTf + (size_t)NE*N4E;
    size_t o_WhhTb    = o_WihTb + (size_t)NI*N4E;
    size_t o_WhT      = o_WhhTb + (size_t)NE*N4E;
    size_t o_WeT      = o_WhT   + (size_t)ND*ND;
    size_t o_WdT      = o_WeT   + (size_t)NTE*ND;
    size_t o_WhhTd    = o_WdT   + (size_t)NTE*N4D;
    size_t o_zc       = o_WhhTd + (size_t)ND*N4D;
    size_t o_wy       = o_zc    + (size_t)NB*N4D;
    size_t total      = o_wy    + (size_t)N4D;
    if (ws_size < total*sizeof(float)) return;  // workspace too small: bail

    auto T = [&](size_t dsto, const float* src, int R, int C, int ld, int off){
        int n = R*C;
        k_transpose<<<dim3((n+255)/256), dim3(256), 0, stream>>>(ws+dsto, src, R, C, ld, off);
    };
    T(o_WihTf, Wih_f, N4E, NI, NI, 0);
    T(o_WhhTf, Whh_f, N4E, NE, NE, 0);
    T(o_WihTb, Wih_b, N4E, NI, NI, 0);
    T(o_WhhTb, Whh_b, N4E, NE, NE, 0);
    T(o_WhT,   W_attn, ND, ND, ND+NTE, 0);
    T(o_WeT,   W_attn, ND, NTE, ND+NTE, ND);
    T(o_WdT,   Wih_d, N4D, NTE, NTE+1, 1);
    T(o_WhhTd, Whh_d, N4D, ND, ND, 0);
    k_pack_wy<<<dim3(4), dim3(256), 0, stream>>>(ws+o_wy, Wih_d);
    k_zc<<<dim3(NB), dim3(256), 0, stream>>>(ws+o_zc, ws+o_WhhTd, dec_h0, b_d);

    k_enc<<<dim3(2*NB), dim3(512), 0, stream>>>(x, enc_h0, enc_c0,
        ws+o_WihTf, ws+o_WhhTf, b_f, ws+o_WihTb, ws+o_WhhTb, b_b, ws+o_enc_out);

    k_encproj<<<dim3(NS/16, NB), dim3(256), 0, stream>>>(ws+o_enc_out, ws+o_WeT, b_attn,
        ws+o_encprojT);

    k_dec<<<dim3(NB), dim3(1024), 0, stream>>>(ws+o_enc_out, ws+o_encprojT,
        ws+o_WhT, v, ws+o_zc, ws+o_wy, ws+o_WdT, dec_h0, dec_c0, W_lin, b_lin, out);
}

// Round 2
// 30159.299 us; speedup vs baseline: 1.5118x; 1.5118x over previous
//
#include <hip/hip_runtime.h>
#include <hip/hip_bf16.h>

#define NB 64
#define NS 512
#define NI 64
#define NE 256
#define ND 256
#define N4E 1024
#define N4D 1024
#define NTE 512   // 2*E
#define G 4
#define SLICE 128 // NS/G
#define CELLS 64  // ND/G

__device__ __forceinline__ float fsig(float x){
    return __fdividef(1.f, 1.f + __expf(-x));
}
__device__ __forceinline__ float ftanh(float x){
    x = fminf(10.f, fmaxf(-10.f, x));
    float e = __expf(2.f*x);
    return 1.f - __fdividef(2.f, e + 1.f);
}
__device__ __forceinline__ float wave_sum(float v){
    #pragma unroll
    for (int o=32;o>0;o>>=1) v += __shfl_xor(v, o, 64);
    return v;
}
__device__ __forceinline__ float wave_max(float v){
    #pragma unroll
    for (int o=32;o>0;o>>=1) v = fmaxf(v, __shfl_xor(v, o, 64));
    return v;
}
__device__ __forceinline__ float blo(unsigned u){ return __uint_as_float(u<<16); }
__device__ __forceinline__ float bhi(unsigned u){ return __uint_as_float(u & 0xffff0000u); }

// fp32 transpose: dst[c*R + r] = src[r*ld + off + c]
__global__ void k_transpose(float* __restrict__ dst, const float* __restrict__ src,
                            int R, int C, int ld, int off){
    int idx = blockIdx.x*256 + threadIdx.x;
    if (idx >= R*C) return;
    int r = idx / C, c = idx - r*C;
    dst[(size_t)c*R + r] = src[(size_t)r*ld + off + c];
}
// bf16 transpose: dst[c*R + r] = bf16(src[r*ld + off + c])
__global__ void k_transpose16(__hip_bfloat16* __restrict__ dst, const float* __restrict__ src,
                              int R, int C, int ld, int off){
    int idx = blockIdx.x*256 + threadIdx.x;
    if (idx >= R*C) return;
    int r = idx / C, c = idx - r*C;
    dst[(size_t)c*R + r] = __float2bfloat16(src[(size_t)r*ld + off + c]);
}

__global__ void k_pack_wy(float* __restrict__ wy, const float* __restrict__ Wih_d){
    int j = blockIdx.x*256 + threadIdx.x;
    if (j < N4D) wy[j] = Wih_d[(size_t)j*(NTE+1)];
}

// WdTg16[q][e][jj] = bf16(Wih_d[ (jj>>6)*256 + q*64 + (jj&63) ][ 1 + e ])
__global__ void k_pack_wdtg(__hip_bfloat16* __restrict__ dst, const float* __restrict__ Wih_d){
    int idx = blockIdx.x*256 + threadIdx.x;   // total 4*512*256 = 524288
    int q = idx >> 17, rem = idx & 131071;
    int e = rem >> 8, jj = rem & 255;
    int j = ((jj>>6)<<8) + (q<<6) + (jj&63);
    dst[idx] = __float2bfloat16(Wih_d[(size_t)j*(NTE+1) + 1 + e]);
}

// zc[b][j] = b_d[j] + sum_d h0d[b][d] * Whh_d[j][d]   (WhhTd is [d][j] fp32)
__global__ void k_zc(float* __restrict__ zc, const float* __restrict__ WhhTd,
                     const float* __restrict__ h0d, const float* __restrict__ b_d){
    int b = blockIdx.x, tid = threadIdx.x;
    __shared__ float h0[ND];
    if (tid < ND) h0[tid] = h0d[b*ND + tid];
    __syncthreads();
    for (int j = tid; j < N4D; j += 256){
        float acc = b_d[j];
        #pragma unroll 8
        for (int d=0; d<ND; ++d) acc = fmaf(h0[d], WhhTd[d*N4D + j], acc);
        zc[b*N4D + j] = acc;
    }
}

// decoder shared-state init: hG = dec_h0, yG = 0, ctr = 0
__global__ void k_dec_init(float* __restrict__ hG, float* __restrict__ yG,
                           unsigned* __restrict__ ctr, const float* __restrict__ dec_h0){
    int b = blockIdx.x, tid = threadIdx.x;
    hG[b*ND + tid] = dec_h0[b*ND + tid];
    if (tid < G) yG[b*G + tid] = 0.f;
    if (tid == 0) ctr[b] = 0u;
}

// Persistent bidirectional encoder: one block per (dir, batch), 512 threads,
// bf16 weights (u32 = 2 adjacent j columns), fp32 state/accumulate.
__global__ __launch_bounds__(512) void k_enc(
    const float* __restrict__ x, const float* __restrict__ eh0, const float* __restrict__ ec0,
    const __hip_bfloat16* __restrict__ WihTf, const __hip_bfloat16* __restrict__ WhhTf, const float* __restrict__ bf,
    const __hip_bfloat16* __restrict__ WihTb, const __hip_bfloat16* __restrict__ WhhTb, const float* __restrict__ bb,
    float* __restrict__ enc_out)
{
    int bid = blockIdx.x;
    int dir = bid & 1, b = bid >> 1;
    const unsigned* Wih2 = (const unsigned*)(dir ? WihTb : WihTf);  // [i][512] j-pairs
    const unsigned* Whh2 = (const unsigned*)(dir ? WhhTb : WhhTf);  // [d][512]
    const float*  bias = dir ? bb : bf;
    int tid = threadIdx.x;
    __shared__ float h[NE], c[NE], xt[NI], z[N4E];
    __shared__ float2 bl[512];
    bl[tid] = ((const float2*)bias)[tid];
    if (tid < NE){
        h[tid] = eh0[(dir*NB + b)*NE + tid];
        c[tid] = ec0[(dir*NB + b)*NE + tid];
    }
    __syncthreads();
    for (int t=0; t<NS; ++t){
        int st = dir ? (NS-1-t) : t;
        if (tid < NI) xt[tid] = x[((size_t)b*NS + st)*NI + tid];
        __syncthreads();
        float2 acc = bl[tid];
        #pragma unroll 8
        for (int i=0;i<NI;++i){
            float xv = xt[i]; unsigned w = Wih2[i*512 + tid];
            acc.x = fmaf(xv, blo(w), acc.x); acc.y = fmaf(xv, bhi(w), acc.y);
        }
        #pragma unroll 8
        for (int d=0;d<NE;++d){
            float hv = h[d]; unsigned w = Whh2[d*512 + tid];
            acc.x = fmaf(hv, blo(w), acc.x); acc.y = fmaf(hv, bhi(w), acc.y);
        }
        ((float2*)z)[tid] = acc;
        __syncthreads();
        if (tid < NE){
            float zi=z[tid], zf=z[NE+tid], zg=z[2*NE+tid], zo=z[3*NE+tid];
            float cn = fsig(zf)*c[tid] + fsig(zi)*ftanh(zg);
            float hn = fsig(zo)*ftanh(cn);
            c[tid]=cn; h[tid]=hn;
            enc_out[((size_t)b*NS + st)*NTE + dir*NE + tid] = hn;
        }
        __syncthreads();
    }
}

// enc_projT[b][d][s] = b_attn[d] + sum_e enc_out[b][s][e] * W_attn[d][256+e]
__global__ __launch_bounds__(256) void k_encproj(const float* __restrict__ enc_out,
        const float* __restrict__ WeT, const float* __restrict__ b_attn,
        float* __restrict__ enc_projT){
    int b = blockIdx.y, s0 = blockIdx.x*16, tid = threadIdx.x;
    __shared__ float tile[16*NTE];
    for (int k=0;k<32;++k){
        int li = k*256 + tid;
        tile[li] = enc_out[((size_t)b*NS + s0 + (li>>9))*NTE + (li&511)];
    }
    __syncthreads();
    float acc[16];
    float ba = b_attn[tid];
    #pragma unroll
    for (int sl=0;sl<16;++sl) acc[sl]=ba;
    for (int e=0;e<NTE;++e){
        float w = WeT[e*ND + tid];
        #pragma unroll
        for (int sl=0;sl<16;++sl) acc[sl] = fmaf(tile[sl*NTE+e], w, acc[sl]);
    }
    float4* dst = (float4*)(enc_projT + ((size_t)b*ND + tid)*NS + s0);
    #pragma unroll
    for (int q=0;q<4;++q) dst[q] = make_float4(acc[4*q],acc[4*q+1],acc[4*q+2],acc[4*q+3]);
}

// Cooperative decoder: 256 blocks = 64 batches x 4 slices, 1024 threads.
// Block (b,q): s-slice [q*128,(q+1)*128), cells d in [q*64,(q+1)*64).
__global__ __launch_bounds__(1024) void k_dec(
    const float* __restrict__ eo_all,   // [b][s][e] fp32
    const float* __restrict__ ep_all,   // [b][d][s] fp32
    const __hip_bfloat16* __restrict__ WhT16,  // [k][d] bf16
    const float* __restrict__ v,
    const float* __restrict__ zc, const float* __restrict__ wy,
    const __hip_bfloat16* __restrict__ WdTg16, // [q][e][jj] bf16
    const float* __restrict__ dec_c0,
    const float* __restrict__ W_lin, const float* __restrict__ b_lin,
    float* __restrict__ hG, float* __restrict__ yG,
    float* __restrict__ ctxG, float* __restrict__ msG,
    unsigned* __restrict__ ctr,
    float* __restrict__ out)
{
    int bid = blockIdx.x;
    int b = bid & 63, q = bid >> 6;
    int tid = threadIdx.x;

    __shared__ float part[2048];
    __shared__ float h_l[ND], hproj[ND], v_l[ND];
    __shared__ float scores_raw[SLICE], scores_l[SLICE];
    __shared__ float ctx_l[NTE];
    __shared__ float z_l[256], zc_l[256], wy_l[256];
    __shared__ float c0_l[CELLS], wlh_l[CELLS], wlc_l[SLICE];
    __shared__ float msbuf[2*G];
    __shared__ float wred[16];
    __shared__ float scal[4];   // 0: local max, 2: y_prev

    const unsigned* WhTp  = (const unsigned*)WhT16;          // [k][128] d-pairs
    const unsigned* WdTp  = (const unsigned*)WdTg16 + (size_t)q*NTE*128; // [e][128] jj-pairs
    const float* ep = ep_all + (size_t)b*ND*NS + q*SLICE;    // ep[d][s0+..]
    const float* eo = eo_all + ((size_t)b*NS + q*SLICE)*NTE; // eo[s0+..][e]
    float blin = b_lin[0];

    if (tid < 256){
        int jj = tid;
        int j = ((jj>>6)<<8) + (q<<6) + (jj&63);
        zc_l[jj] = zc[b*N4D + j];
        wy_l[jj] = wy[j];
        v_l[tid] = v[tid];
    }
    if (tid < CELLS){
        c0_l[tid]  = dec_c0[b*ND + q*CELLS + tid];
        wlh_l[tid] = W_lin[q*CELLS + tid];
    }
    if (tid < SLICE) wlc_l[tid] = W_lin[ND + q*SLICE + tid];
    __syncthreads();

    for (int t=0; t<NS; ++t){
        // ---- A: load h(t-1), y(t-1); compute hproj ----
        if (tid < ND) h_l[tid] = hG[b*ND + tid];
        if (tid == 0){
            float y = 0.f;
            if (t > 0){
                y = blin + yG[b*G+0] + yG[b*G+1] + yG[b*G+2] + yG[b*G+3];
                if (q == 0) out[(size_t)b*NS + (t-1)] = y;
            }
            scal[2] = y;
        }
        __syncthreads();
        {
            int d2 = tid & 127, kq = tid >> 7;       // 8 groups x 32 k
            float ax = 0.f, ay = 0.f;
            #pragma unroll 8
            for (int kk=0; kk<32; ++kk){
                int k = kq*32 + kk;
                unsigned w = WhTp[k*128 + d2];
                float hv = h_l[k];
                ax = fmaf(hv, blo(w), ax); ay = fmaf(hv, bhi(w), ay);
            }
            part[kq*256 + 2*d2]   = ax;
            part[kq*256 + 2*d2+1] = ay;
        }
        __syncthreads();
        if (tid < ND){
            float s = 0.f;
            #pragma unroll
            for (int r=0;r<8;++r) s += part[r*256 + tid];
            hproj[tid] = s;
        }
        __syncthreads();
        // ---- B: scores for s-slice + local online softmax ----
        {
            int sl = tid & 127, dg = tid >> 7;       // 8 groups x 32 d
            float sc = 0.f;
            const float* eprow = ep + sl;
            #pragma unroll 4
            for (int dd=0; dd<32; ++dd){
                int d = dg*32 + dd;
                sc = fmaf(v_l[d], ftanh(eprow[(size_t)d*NS] + hproj[d]), sc);
            }
            part[dg*128 + sl] = sc;
        }
        __syncthreads();
        if (tid < SLICE){
            float s = 0.f;
            #pragma unroll
            for (int r=0;r<8;++r) s += part[r*128 + tid];
            scores_raw[tid] = s;
            float wm = wave_max(s);
            if ((tid&63)==0) wred[tid>>6] = wm;
        }
        __syncthreads();
        if (tid == 0) scal[0] = fmaxf(wred[0], wred[1]);
        __syncthreads();
        if (tid < SLICE){
            float e = __expf(scores_raw[tid] - scal[0]);
            scores_l[tid] = e;
            float s = wave_sum(e);
            if ((tid&63)==0) wred[2+(tid>>6)] = s;
        }
        __syncthreads();
        if (tid == 0){
            msG[(b*G+q)*2+0] = scal[0];
            msG[(b*G+q)*2+1] = wred[2]+wred[3];
        }
        // ---- C: context partial ----
        {
            int e = tid & 511, half = tid >> 9;       // 2 x 64 s
            float acc = 0.f;
            const float* eor = eo + (size_t)(half*64)*NTE + e;
            #pragma unroll 4
            for (int ss=0; ss<64; ++ss)
                acc = fmaf(scores_l[half*64+ss], eor[(size_t)ss*NTE], acc);
            part[half*512 + e] = acc;
        }
        __syncthreads();
        if (tid < NTE) ctxG[(size_t)(b*G+q)*NTE + tid] = part[tid] + part[512+tid];
        __syncthreads();
        // ---- barrier 1 ----
        if (tid == 0){
            __threadfence();
            __hip_atomic_fetch_add(&ctr[b], 1u, __ATOMIC_RELEASE, __HIP_MEMORY_SCOPE_AGENT);
            unsigned tgt = (unsigned)(t*2*G + G);
            while (__hip_atomic_load(&ctr[b], __ATOMIC_RELAXED, __HIP_MEMORY_SCOPE_AGENT) < tgt)
                __builtin_amdgcn_s_sleep(1);
            __threadfence();
        }
        __syncthreads();
        // ---- D: merge softmax, z j-slice, gates, y partial ----
        if (tid < 2*G) msbuf[tid] = msG[b*G*2 + tid];
        __syncthreads();
        float m = fmaxf(fmaxf(msbuf[0], msbuf[2]), fmaxf(msbuf[4], msbuf[6]));
        float w0 = __expf(msbuf[0]-m), w1 = __expf(msbuf[2]-m),
              w2 = __expf(msbuf[4]-m), w3 = __expf(msbuf[6]-m);
        float inv = __fdividef(1.f, msbuf[1]*w0 + msbuf[3]*w1 + msbuf[5]*w2 + msbuf[7]*w3);
        if (tid < NTE){
            const float* cg = ctxG + (size_t)b*G*NTE + tid;
            float cacc = cg[0]*w0 + cg[NTE]*w1 + cg[2*NTE]*w2 + cg[3*NTE]*w3;
            ctx_l[tid] = cacc * inv;
        }
        __syncthreads();
        {
            int jj2 = tid & 127, eq = tid >> 7;       // 8 groups x 64 e
            float ax = 0.f, ay = 0.f;
            #pragma unroll 8
            for (int ee=0; ee<64; ++ee){
                int e = eq*64 + ee;
                unsigned w = WdTp[e*128 + jj2];
                float cv = ctx_l[e];
                ax = fmaf(cv, blo(w), ax); ay = fmaf(cv, bhi(w), ay);
            }
            part[eq*256 + 2*jj2]   = ax;
            part[eq*256 + 2*jj2+1] = ay;
        }
        __syncthreads();
        if (tid < 256){
            float s = zc_l[tid] + scal[2]*wy_l[tid];
            #pragma unroll
            for (int r=0;r<8;++r) s += part[r*256 + tid];
            z_l[tid] = s;
        }
        __syncthreads();
        float yp = 0.f;
        if (tid < CELLS){
            float zi=z_l[tid], zf=z_l[64+tid], zg=z_l[128+tid], zo=z_l[192+tid];
            float cn = fsig(zf)*c0_l[tid] + fsig(zi)*ftanh(zg);
            float hn = fsig(zo)*ftanh(cn);
            hG[b*ND + q*CELLS + tid] = hn;
            yp = hn * wlh_l[tid];
        } else if (tid < CELLS + SLICE){
            yp = ctx_l[q*SLICE + (tid - CELLS)] * wlc_l[tid - CELLS];
        }
        {
            float s = wave_sum(yp);
            if ((tid&63)==0 && tid < 192) wred[8+(tid>>6)] = s;
        }
        __syncthreads();
        if (tid == 0) yG[b*G + q] = wred[8]+wred[9]+wred[10];
        __syncthreads();
        // ---- barrier 2 ----
        if (tid == 0){
            __threadfence();
            __hip_atomic_fetch_add(&ctr[b], 1u, __ATOMIC_RELEASE, __HIP_MEMORY_SCOPE_AGENT);
            unsigned tgt = (unsigned)(t*2*G + 2*G);
            while (__hip_atomic_load(&ctr[b], __ATOMIC_RELAXED, __HIP_MEMORY_SCOPE_AGENT) < tgt)
                __builtin_amdgcn_s_sleep(1);
            __threadfence();
        }
        __syncthreads();
    }
    if (q == 0 && tid == 0){
        out[(size_t)b*NS + (NS-1)] = blin + yG[b*G+0] + yG[b*G+1] + yG[b*G+2] + yG[b*G+3];
    }
}

extern "C" void kernel_launch(void* const* d_in, const int* in_sizes, int n_in,
                              void* d_out, int out_size, void* d_ws, size_t ws_size,
                              hipStream_t stream){
    const float* x      = (const float*)d_in[0];
    const float* enc_h0 = (const float*)d_in[1];
    const float* enc_c0 = (const float*)d_in[2];
    const float* dec_h0 = (const float*)d_in[3];
    const float* dec_c0 = (const float*)d_in[4];
    const float* Wih_f  = (const float*)d_in[5];
    const float* Whh_f  = (const float*)d_in[6];
    const float* b_f    = (const float*)d_in[7];
    const float* Wih_b  = (const float*)d_in[8];
    const float* Whh_b  = (const float*)d_in[9];
    const float* b_b    = (const float*)d_in[10];
    const float* W_attn = (const float*)d_in[11];
    const float* b_attn = (const float*)d_in[12];
    const float* v      = (const float*)d_in[13];
    const float* Wih_d  = (const float*)d_in[14];
    const float* Whh_d  = (const float*)d_in[15];
    const float* b_d    = (const float*)d_in[16];
    const float* W_lin  = (const float*)d_in[17];
    const float* b_lin  = (const float*)d_in[18];
    float* out = (float*)d_out;
    char* ws   = (char*)d_ws;

    size_t off = 0;
    auto alloc = [&](size_t bytes)->size_t{ size_t o = off; off += (bytes + 255) & ~(size_t)255; return o; };
    size_t o_eo     = alloc((size_t)NB*NS*NTE*4);      // enc_out fp32
    size_t o_ep     = alloc((size_t)NB*ND*NS*4);       // enc_projT fp32
    size_t o_WihTf  = alloc((size_t)NI*N4E*2);
    size_t o_WhhTf  = alloc((size_t)NE*N4E*2);
    size_t o_WihTb  = alloc((size_t)NI*N4E*2);
    size_t o_WhhTb  = alloc((size_t)NE*N4E*2);
    size_t o_WhT16  = alloc((size_t)ND*ND*2);
    size_t o_WeT    = alloc((size_t)NTE*ND*4);
    size_t o_WdTg   = alloc((size_t)G*NTE*256*2);
    size_t o_WhhTd  = alloc((size_t)ND*N4D*4);
    size_t o_zc     = alloc((size_t)NB*N4D*4);
    size_t o_wy     = alloc((size_t)N4D*4);
    size_t o_hG     = alloc((size_t)NB*ND*4);
    size_t o_yG     = alloc((size_t)NB*G*4);
    size_t o_ctxG   = alloc((size_t)NB*G*NTE*4);
    size_t o_msG    = alloc((size_t)NB*G*2*4);
    size_t o_ctr    = alloc((size_t)NB*4);
    if (ws_size < off) return;

    auto F   = [&](size_t o)->float*{ return (float*)(ws + o); };
    auto H16 = [&](size_t o)->__hip_bfloat16*{ return (__hip_bfloat16*)(ws + o); };

    auto T32 = [&](size_t dsto, const float* src, int R, int C, int ld, int offc){
        int n = R*C;
        k_transpose<<<dim3((n+255)/256), dim3(256), 0, stream>>>(F(dsto), src, R, C, ld, offc);
    };
    auto T16 = [&](size_t dsto, const float* src, int R, int C, int ld, int offc){
        int n = R*C;
        k_transpose16<<<dim3((n+255)/256), dim3(256), 0, stream>>>(H16(dsto), src, R, C, ld, offc);
    };
    T16(o_WihTf, Wih_f, N4E, NI, NI, 0);
    T16(o_WhhTf, Whh_f, N4E, NE, NE, 0);
    T16(o_WihTb, Wih_b, N4E, NI, NI, 0);
    T16(o_WhhTb, Whh_b, N4E, NE, NE, 0);
    T16(o_WhT16, W_attn, ND, ND, ND+NTE, 0);
    T32(o_WeT,   W_attn, ND, NTE, ND+NTE, ND);
    T32(o_WhhTd, Whh_d, N4D, ND, ND, 0);
    k_pack_wdtg<<<dim3((G*NTE*256)/256), dim3(256), 0, stream>>>(H16(o_WdTg), Wih_d);
    k_pack_wy<<<dim3(4), dim3(256), 0, stream>>>(F(o_wy), Wih_d);
    k_zc<<<dim3(NB), dim3(256), 0, stream>>>(F(o_zc), F(o_WhhTd), dec_h0, b_d);
    k_dec_init<<<dim3(NB), dim3(256), 0, stream>>>(F(o_hG), F(o_yG), (unsigned*)(ws+o_ctr), dec_h0);

    k_enc<<<dim3(2*NB), dim3(512), 0, stream>>>(x, enc_h0, enc_c0,
        H16(o_WihTf), H16(o_WhhTf), b_f, H16(o_WihTb), H16(o_WhhTb), b_b, F(o_eo));

    k_encproj<<<dim3(NS/16, NB), dim3(256), 0, stream>>>(F(o_eo), F(o_WeT), b_attn, F(o_ep));

    k_dec<<<dim3(NB*G), dim3(1024), 0, stream>>>(F(o_eo), F(o_ep),
        H16(o_WhT16), v, F(o_zc), F(o_wy), H16(o_WdTg), dec_c0, W_lin, b_lin,
        F(o_hG), F(o_yG), F(o_ctxG), F(o_msG), (unsigned*)(ws+o_ctr), out);
}

// Round 3
// 19513.425 us; speedup vs baseline: 2.3366x; 1.5456x over previous
//
#include <hip/hip_runtime.h>
#include <hip/hip_bf16.h>

#define NB 64
#define NS 512
#define NI 64
#define NE 256
#define ND 256
#define N4E 1024
#define N4D 1024
#define NTE 512   // 2*E
#define G 4
#define SLICE 128 // NS/G
#define CELLS 64  // ND/G

__device__ __forceinline__ float fsig(float x){
    return __fdividef(1.f, 1.f + __expf(-x));
}
__device__ __forceinline__ float ftanh(float x){
    x = fminf(10.f, fmaxf(-10.f, x));
    float e = __expf(2.f*x);
    return 1.f - __fdividef(2.f, e + 1.f);
}
__device__ __forceinline__ float wave_sum(float v){
    #pragma unroll
    for (int o=32;o>0;o>>=1) v += __shfl_xor(v, o, 64);
    return v;
}
__device__ __forceinline__ float wave_max(float v){
    #pragma unroll
    for (int o=32;o>0;o>>=1) v = fmaxf(v, __shfl_xor(v, o, 64));
    return v;
}
__device__ __forceinline__ float blo(unsigned u){ return __uint_as_float(u<<16); }
__device__ __forceinline__ float bhi(unsigned u){ return __uint_as_float(u & 0xffff0000u); }
__device__ __forceinline__ unsigned short bfbits(float f){
    __hip_bfloat16 h = __float2bfloat16(f);
    return *(unsigned short*)&h;
}
// relaxed agent-scope accessors: single instructions, no cache-wide ops
__device__ __forceinline__ float ld_agf(const float* p){
    return __hip_atomic_load(p, __ATOMIC_RELAXED, __HIP_MEMORY_SCOPE_AGENT);
}
__device__ __forceinline__ void st_agf(float* p, float v){
    __hip_atomic_store(p, v, __ATOMIC_RELAXED, __HIP_MEMORY_SCOPE_AGENT);
}

// group barrier: __syncthreads drains each wave's outstanding (write-through)
// stores before tid0 bumps the flag -> data visible at coherent point first.
__device__ __forceinline__ void groupbar(unsigned* c, unsigned tgt, int tid){
    __syncthreads();
    if (tid == 0){
        __hip_atomic_fetch_add(c, 1u, __ATOMIC_RELAXED, __HIP_MEMORY_SCOPE_AGENT);
        while (__hip_atomic_load(c, __ATOMIC_RELAXED, __HIP_MEMORY_SCOPE_AGENT) < tgt)
            __builtin_amdgcn_s_sleep(2);
    }
    __syncthreads();
}

// fp32 transpose: dst[c*R + r] = src[r*ld + off + c]
__global__ void k_transpose(float* __restrict__ dst, const float* __restrict__ src,
                            int R, int C, int ld, int off){
    int idx = blockIdx.x*256 + threadIdx.x;
    if (idx >= R*C) return;
    int r = idx / C, c = idx - r*C;
    dst[(size_t)c*R + r] = src[(size_t)r*ld + off + c];
}
// bf16 transpose
__global__ void k_transpose16(__hip_bfloat16* __restrict__ dst, const float* __restrict__ src,
                              int R, int C, int ld, int off){
    int idx = blockIdx.x*256 + threadIdx.x;
    if (idx >= R*C) return;
    int r = idx / C, c = idx - r*C;
    dst[(size_t)c*R + r] = __float2bfloat16(src[(size_t)r*ld + off + c]);
}

__global__ void k_pack_wy(float* __restrict__ wy, const float* __restrict__ Wih_d){
    int j = blockIdx.x*256 + threadIdx.x;
    if (j < N4D) wy[j] = Wih_d[(size_t)j*(NTE+1)];
}

// WdTg16[q][e][jj] = bf16(Wih_d[ (jj>>6)*256 + q*64 + (jj&63) ][ 1 + e ])
__global__ void k_pack_wdtg(__hip_bfloat16* __restrict__ dst, const float* __restrict__ Wih_d){
    int idx = blockIdx.x*256 + threadIdx.x;   // total 4*512*256 = 524288
    int q = idx >> 17, rem = idx & 131071;
    int e = rem >> 8, jj = rem & 255;
    int j = ((jj>>6)<<8) + (q<<6) + (jj&63);
    dst[idx] = __float2bfloat16(Wih_d[(size_t)j*(NTE+1) + 1 + e]);
}

// zc[b][j] = b_d[j] + sum_d h0d[b][d] * Whh_d[j][d]   (WhhTd is [d][j] fp32)
__global__ void k_zc(float* __restrict__ zc, const float* __restrict__ WhhTd,
                     const float* __restrict__ h0d, const float* __restrict__ b_d){
    int b = blockIdx.x, tid = threadIdx.x;
    __shared__ float h0[ND];
    if (tid < ND) h0[tid] = h0d[b*ND + tid];
    __syncthreads();
    for (int j = tid; j < N4D; j += 256){
        float acc = b_d[j];
        #pragma unroll 8
        for (int d=0; d<ND; ++d) acc = fmaf(h0[d], WhhTd[d*N4D + j], acc);
        zc[b*N4D + j] = acc;
    }
}

__global__ void k_dec_init(float* __restrict__ hG, float* __restrict__ yG,
                           unsigned* __restrict__ ctr, const float* __restrict__ dec_h0){
    int b = blockIdx.x, tid = threadIdx.x;
    hG[b*ND + tid] = dec_h0[b*ND + tid];
    if (tid < G) yG[b*G + tid] = 0.f;
    if (tid == 0) ctr[b] = 0u;
}

// Persistent bidirectional encoder: one block per (dir, batch), 512 threads,
// bf16 weights (u32 = 2 adjacent j columns), fp32 state, bf16 output.
__global__ __launch_bounds__(512) void k_enc(
    const float* __restrict__ x, const float* __restrict__ eh0, const float* __restrict__ ec0,
    const __hip_bfloat16* __restrict__ WihTf, const __hip_bfloat16* __restrict__ WhhTf, const float* __restrict__ bf,
    const __hip_bfloat16* __restrict__ WihTb, const __hip_bfloat16* __restrict__ WhhTb, const float* __restrict__ bb,
    __hip_bfloat16* __restrict__ eo16)
{
    int bid = blockIdx.x;
    int dir = bid & 1, b = bid >> 1;
    const unsigned* Wih2 = (const unsigned*)(dir ? WihTb : WihTf);  // [i][512] j-pairs
    const unsigned* Whh2 = (const unsigned*)(dir ? WhhTb : WhhTf);  // [d][512]
    const float*  bias = dir ? bb : bf;
    int tid = threadIdx.x;
    __shared__ float h[NE], c[NE], xt[NI], z[N4E];
    __shared__ float2 bl[512];
    bl[tid] = ((const float2*)bias)[tid];
    if (tid < NE){
        h[tid] = eh0[(dir*NB + b)*NE + tid];
        c[tid] = ec0[(dir*NB + b)*NE + tid];
    }
    __syncthreads();
    for (int t=0; t<NS; ++t){
        int st = dir ? (NS-1-t) : t;
        if (tid < NI) xt[tid] = x[((size_t)b*NS + st)*NI + tid];
        __syncthreads();
        float2 acc = bl[tid];
        #pragma unroll 8
        for (int i=0;i<NI;++i){
            float xv = xt[i]; unsigned w = Wih2[i*512 + tid];
            acc.x = fmaf(xv, blo(w), acc.x); acc.y = fmaf(xv, bhi(w), acc.y);
        }
        #pragma unroll 8
        for (int d=0;d<NE;++d){
            float hv = h[d]; unsigned w = Whh2[d*512 + tid];
            acc.x = fmaf(hv, blo(w), acc.x); acc.y = fmaf(hv, bhi(w), acc.y);
        }
        ((float2*)z)[tid] = acc;
        __syncthreads();
        if (tid < NE){
            float zi=z[tid], zf=z[NE+tid], zg=z[2*NE+tid], zo=z[3*NE+tid];
            float cn = fsig(zf)*c[tid] + fsig(zi)*ftanh(zg);
            float hn = fsig(zo)*ftanh(cn);
            c[tid]=cn; h[tid]=hn;
            eo16[((size_t)b*NS + st)*NTE + dir*NE + tid] = __float2bfloat16(hn);
        }
        __syncthreads();
    }
}

// ep_pk[b][q][dp][s] (u32 = bf16 pair d=2dp,2dp+1) from bf16 enc_out.
__global__ __launch_bounds__(256) void k_encproj(const unsigned* __restrict__ eo32,
        const float* __restrict__ WeT, const float* __restrict__ b_attn,
        unsigned short* __restrict__ ep_pk16){
    int b = blockIdx.y, s0 = blockIdx.x*16, tid = threadIdx.x;
    __shared__ float tile[16*NTE];
    {
        const unsigned* eop = eo32 + (size_t)(b*NS + s0)*256;
        for (int k=0;k<32;++k){
            int wi = k*256 + tid;
            unsigned w = eop[wi];
            int sl = wi>>8, ew = wi&255;
            tile[sl*NTE + 2*ew]   = blo(w);
            tile[sl*NTE + 2*ew+1] = bhi(w);
        }
    }
    __syncthreads();
    float acc[16];
    float ba = b_attn[tid];
    #pragma unroll
    for (int sl=0;sl<16;++sl) acc[sl]=ba;
    #pragma unroll 4
    for (int e4=0;e4<128;++e4){
        float w0 = WeT[(4*e4+0)*ND+tid];
        float w1 = WeT[(4*e4+1)*ND+tid];
        float w2 = WeT[(4*e4+2)*ND+tid];
        float w3 = WeT[(4*e4+3)*ND+tid];
        #pragma unroll
        for (int sl=0;sl<16;++sl){
            const float4 tv = *(const float4*)&tile[sl*NTE + 4*e4];
            acc[sl] = fmaf(tv.x,w0,fmaf(tv.y,w1,fmaf(tv.z,w2,fmaf(tv.w,w3,acc[sl]))));
        }
    }
    #pragma unroll
    for (int sl=0;sl<16;++sl){
        int s = s0+sl;
        size_t wdi = ((size_t)(b*4 + (s>>7))*128 + (tid>>1))*128 + (s&127);
        ep_pk16[wdi*2 + (tid&1)] = bfbits(acc[sl]);
    }
}

// Cooperative decoder: 256 blocks = 64 batches x 4 slices, 1024 threads.
// eo slice in registers, ep slice in LDS; WhT+WdT stream from per-XCD L2.
// Cross-block comm exclusively via relaxed agent atomics (no fences).
__global__ __launch_bounds__(1024, 4) void k_dec(
    const unsigned* __restrict__ eo32,     // [b*s][256] bf16 e-pairs
    const unsigned* __restrict__ ep_pk,    // [b][q][128 dp][128 s] u32
    const unsigned* __restrict__ WhTp,     // [k 256][128] bf16 d-pairs
    const float* __restrict__ v,
    const float* __restrict__ zc, const float* __restrict__ wy,
    const unsigned* __restrict__ WdTp_all, // [q][512 e][128] bf16 jj-pairs
    const float* __restrict__ dec_c0,
    const float* __restrict__ W_lin, const float* __restrict__ b_lin,
    float* __restrict__ hG, float* __restrict__ yG,
    float* __restrict__ ctxG, float* __restrict__ msG,
    unsigned* __restrict__ ctr,
    float* __restrict__ out)
{
    int bid = blockIdx.x;
    int b = bid & 63, q = bid >> 6;
    int tid = threadIdx.x;

    __shared__ unsigned ep_lds[16384];   // 64 KB: [128 dp][128 s]
    __shared__ float part[2048];
    __shared__ float h_l[ND];
    __shared__ float2 hv[ND];            // (v[d], hproj[d])
    __shared__ float v_l[ND];
    __shared__ float scores_l[SLICE];
    __shared__ float ctx_l[NTE];
    __shared__ float z_l[256], zc_l[256], wy_l[256];
    __shared__ float c0_l[CELLS], wlh_l[CELLS], wlc_l[SLICE];
    __shared__ float msbuf[8];
    __shared__ float wred[16];
    __shared__ float smax, yprev;

    const unsigned* WdTp = WdTp_all + (size_t)q*NTE*128;

    for (int i=tid; i<16384; i+=1024)
        ep_lds[i] = ep_pk[(size_t)(b*4+q)*16384 + i];
    unsigned eo_reg[32];
    {
        int ep2 = tid & 255, sq = tid >> 8;
        const unsigned* eop = eo32 + (size_t)(b*NS + q*SLICE + sq*32)*256 + ep2;
        #pragma unroll
        for (int ss=0; ss<32; ++ss) eo_reg[ss] = eop[(size_t)ss*256];
    }
    if (tid < 256){
        int jj = tid;
        int j = ((jj>>6)<<8) + (q<<6) + (jj&63);
        zc_l[jj] = zc[b*N4D + j];
        wy_l[jj] = wy[j];
        v_l[tid] = v[tid];
    }
    if (tid < CELLS){
        c0_l[tid]  = dec_c0[b*ND + q*CELLS + tid];
        wlh_l[tid] = W_lin[q*CELLS + tid];
    }
    if (tid < SLICE) wlc_l[tid] = W_lin[ND + q*SLICE + tid];
    float blin = b_lin[0];
    __syncthreads();

    for (int t=0; t<NS; ++t){
        // ---- A: fetch h(t-1), y(t-1); hproj = h @ WhT ----
        if (tid < ND) h_l[tid] = ld_agf(&hG[b*ND + tid]);
        if (tid == 0){
            float y = 0.f;
            if (t > 0){
                y = blin + ld_agf(&yG[b*G+0]) + ld_agf(&yG[b*G+1])
                         + ld_agf(&yG[b*G+2]) + ld_agf(&yG[b*G+3]);
                if (q == 0) out[(size_t)b*NS + (t-1)] = y;
            }
            yprev = y;
        }
        __syncthreads();
        {
            int d2 = tid & 127, kq = tid >> 7;
            float ax = 0.f, ay = 0.f;
            #pragma unroll 8
            for (int kk=0; kk<32; ++kk){
                int k = kq*32 + kk;
                unsigned w = WhTp[k*128 + d2];
                float hvv = h_l[k];
                ax = fmaf(hvv, blo(w), ax); ay = fmaf(hvv, bhi(w), ay);
            }
            ((float2*)part)[kq*128 + d2] = make_float2(ax, ay);
        }
        __syncthreads();
        if (tid < ND){
            float s = 0.f;
            #pragma unroll
            for (int r=0;r<8;++r) s += part[r*256 + tid];
            hv[tid] = make_float2(v_l[tid], s);
        }
        __syncthreads();
        // ---- B: scores from LDS ep ----
        {
            int sl = tid & 127, dg = tid >> 7;
            float sc = 0.f;
            const unsigned* epl = ep_lds + dg*16*128 + sl;
            #pragma unroll
            for (int k16=0; k16<16; ++k16){
                unsigned w = epl[k16*128];
                int d = dg*32 + 2*k16;
                float2 a0 = hv[d], a1 = hv[d+1];
                sc += a0.x*ftanh(blo(w) + a0.y) + a1.x*ftanh(bhi(w) + a1.y);
            }
            part[dg*128 + sl] = sc;
        }
        __syncthreads();
        if (tid < SLICE){
            float s = 0.f;
            #pragma unroll
            for (int r=0;r<8;++r) s += part[r*128 + tid];
            part[1024 + tid] = s;   // raw scores stash
            float wm = wave_max(s);
            if ((tid&63)==0) wred[tid>>6] = wm;
        }
        __syncthreads();
        if (tid == 0) smax = fmaxf(wred[0], wred[1]);
        __syncthreads();
        if (tid < SLICE){
            float ev = __expf(part[1024 + tid] - smax);
            scores_l[tid] = ev;
            float s = wave_sum(ev);
            if ((tid&63)==0) wred[2+(tid>>6)] = s;
        }
        __syncthreads();
        if (tid == 0){
            st_agf(&msG[(b*G+q)*2+0], smax);
            st_agf(&msG[(b*G+q)*2+1], wred[2]+wred[3]);
        }
        // ---- C: context partial from registers ----
        {
            int ep2 = tid & 255, sq = tid >> 8;
            float ax = 0.f, ay = 0.f;
            #pragma unroll
            for (int ss=0; ss<32; ++ss){
                unsigned w = eo_reg[ss];
                float sc = scores_l[sq*32 + ss];
                ax = fmaf(sc, blo(w), ax); ay = fmaf(sc, bhi(w), ay);
            }
            ((float2*)part)[sq*256 + ep2] = make_float2(ax, ay);
        }
        __syncthreads();
        if (tid < NTE){
            float s = part[tid] + part[512+tid] + part[1024+tid] + part[1536+tid];
            st_agf(&ctxG[(size_t)(b*G+q)*NTE + tid], s);
        }
        groupbar(&ctr[b], (unsigned)(t*2*G + G), tid);
        // ---- D: merge softmax+context; z slice; gates; y partial ----
        if (tid < 2*G) msbuf[tid] = ld_agf(&msG[b*G*2 + tid]);
        __syncthreads();
        float mm = fmaxf(fmaxf(msbuf[0], msbuf[2]), fmaxf(msbuf[4], msbuf[6]));
        float w0 = __expf(msbuf[0]-mm), w1 = __expf(msbuf[2]-mm),
              w2 = __expf(msbuf[4]-mm), w3 = __expf(msbuf[6]-mm);
        float inv = __fdividef(1.f, msbuf[1]*w0 + msbuf[3]*w1 + msbuf[5]*w2 + msbuf[7]*w3);
        if (tid < NTE){
            const float* cg = ctxG + (size_t)b*G*NTE + tid;
            float cacc = ld_agf(cg)*w0 + ld_agf(cg+NTE)*w1
                       + ld_agf(cg+2*NTE)*w2 + ld_agf(cg+3*NTE)*w3;
            ctx_l[tid] = cacc * inv;
        }
        __syncthreads();
        {
            int jj2 = tid & 127, eq = tid >> 7;
            float ax = 0.f, ay = 0.f;
            #pragma unroll 8
            for (int ee=0; ee<64; ++ee){
                int e = eq*64 + ee;
                unsigned w = WdTp[e*128 + jj2];
                float cv = ctx_l[e];
                ax = fmaf(cv, blo(w), ax); ay = fmaf(cv, bhi(w), ay);
            }
            ((float2*)part)[eq*128 + jj2] = make_float2(ax, ay);
        }
        __syncthreads();
        if (tid < 256){
            float s = zc_l[tid] + yprev*wy_l[tid];
            #pragma unroll
            for (int r=0;r<8;++r) s += part[r*256 + tid];
            z_l[tid] = s;
        }
        __syncthreads();
        float yp = 0.f;
        if (tid < CELLS){
            float zi=z_l[tid], zf=z_l[64+tid], zg=z_l[128+tid], zo=z_l[192+tid];
            float cn = fsig(zf)*c0_l[tid] + fsig(zi)*ftanh(zg);
            float hn = fsig(zo)*ftanh(cn);
            st_agf(&hG[b*ND + q*CELLS + tid], hn);
            yp = hn * wlh_l[tid];
        } else if (tid < CELLS + SLICE){
            yp = ctx_l[q*SLICE + (tid - CELLS)] * wlc_l[tid - CELLS];
        }
        {
            float s = wave_sum(yp);
            if ((tid&63)==0 && tid < 192) wred[8+(tid>>6)] = s;
        }
        __syncthreads();
        if (tid == 0) st_agf(&yG[b*G + q], wred[8]+wred[9]+wred[10]);
        groupbar(&ctr[b], (unsigned)(t*2*G + 2*G), tid);
    }
    if (q == 0 && tid == 0){
        out[(size_t)b*NS + (NS-1)] = blin + ld_agf(&yG[b*G+0]) + ld_agf(&yG[b*G+1])
                                          + ld_agf(&yG[b*G+2]) + ld_agf(&yG[b*G+3]);
    }
}

extern "C" void kernel_launch(void* const* d_in, const int* in_sizes, int n_in,
                              void* d_out, int out_size, void* d_ws, size_t ws_size,
                              hipStream_t stream){
    const float* x      = (const float*)d_in[0];
    const float* enc_h0 = (const float*)d_in[1];
    const float* enc_c0 = (const float*)d_in[2];
    const float* dec_h0 = (const float*)d_in[3];
    const float* dec_c0 = (const float*)d_in[4];
    const float* Wih_f  = (const float*)d_in[5];
    const float* Whh_f  = (const float*)d_in[6];
    const float* b_f    = (const float*)d_in[7];
    const float* Wih_b  = (const float*)d_in[8];
    const float* Whh_b  = (const float*)d_in[9];
    const float* b_b    = (const float*)d_in[10];
    const float* W_attn = (const float*)d_in[11];
    const float* b_attn = (const float*)d_in[12];
    const float* v      = (const float*)d_in[13];
    const float* Wih_d  = (const float*)d_in[14];
    const float* Whh_d  = (const float*)d_in[15];
    const float* b_d    = (const float*)d_in[16];
    const float* W_lin  = (const float*)d_in[17];
    const float* b_lin  = (const float*)d_in[18];
    float* out = (float*)d_out;
    char* ws   = (char*)d_ws;

    size_t off = 0;
    auto alloc = [&](size_t bytes)->size_t{ size_t o = off; off += (bytes + 255) & ~(size_t)255; return o; };
    size_t o_eo16   = alloc((size_t)NB*NS*NTE*2);        // bf16 enc_out
    size_t o_eppk   = alloc((size_t)NB*G*128*128*4);     // packed bf16 ep
    size_t o_WihTf  = alloc((size_t)NI*N4E*2);
    size_t o_WhhTf  = alloc((size_t)NE*N4E*2);
    size_t o_WihTb  = alloc((size_t)NI*N4E*2);
    size_t o_WhhTb  = alloc((size_t)NE*N4E*2);
    size_t o_WhT16  = alloc((size_t)ND*ND*2);
    size_t o_WeT    = alloc((size_t)NTE*ND*4);
    size_t o_WdTg   = alloc((size_t)G*NTE*256*2);
    size_t o_WhhTd  = alloc((size_t)ND*N4D*4);
    size_t o_zc     = alloc((size_t)NB*N4D*4);
    size_t o_wy     = alloc((size_t)N4D*4);
    size_t o_hG     = alloc((size_t)NB*ND*4);
    size_t o_yG     = alloc((size_t)NB*G*4);
    size_t o_ctxG   = alloc((size_t)NB*G*NTE*4);
    size_t o_msG    = alloc((size_t)NB*G*2*4);
    size_t o_ctr    = alloc((size_t)NB*4);
    if (ws_size < off) return;

    auto F   = [&](size_t o)->float*{ return (float*)(ws + o); };
    auto U32 = [&](size_t o)->unsigned*{ return (unsigned*)(ws + o); };
    auto H16 = [&](size_t o)->__hip_bfloat16*{ return (__hip_bfloat16*)(ws + o); };

    auto T32 = [&](size_t dsto, const float* src, int R, int C, int ld, int offc){
        int n = R*C;
        k_transpose<<<dim3((n+255)/256), dim3(256), 0, stream>>>(F(dsto), src, R, C, ld, offc);
    };
    auto T16 = [&](size_t dsto, const float* src, int R, int C, int ld, int offc){
        int n = R*C;
        k_transpose16<<<dim3((n+255)/256), dim3(256), 0, stream>>>(H16(dsto), src, R, C, ld, offc);
    };
    T16(o_WihTf, Wih_f, N4E, NI, NI, 0);
    T16(o_WhhTf, Whh_f, N4E, NE, NE, 0);
    T16(o_WihTb, Wih_b, N4E, NI, NI, 0);
    T16(o_WhhTb, Whh_b, N4E, NE, NE, 0);
    T16(o_WhT16, W_attn, ND, ND, ND+NTE, 0);
    T32(o_WeT,   W_attn, ND, NTE, ND+NTE, ND);
    T32(o_WhhTd, Whh_d, N4D, ND, ND, 0);
    k_pack_wdtg<<<dim3((G*NTE*256)/256), dim3(256), 0, stream>>>(H16(o_WdTg), Wih_d);
    k_pack_wy<<<dim3(4), dim3(256), 0, stream>>>(F(o_wy), Wih_d);
    k_zc<<<dim3(NB), dim3(256), 0, stream>>>(F(o_zc), F(o_WhhTd), dec_h0, b_d);
    k_dec_init<<<dim3(NB), dim3(256), 0, stream>>>(F(o_hG), F(o_yG), (unsigned*)(ws+o_ctr), dec_h0);

    k_enc<<<dim3(2*NB), dim3(512), 0, stream>>>(x, enc_h0, enc_c0,
        H16(o_WihTf), H16(o_WhhTf), b_f, H16(o_WihTb), H16(o_WhhTb), b_b, H16(o_eo16));

    k_encproj<<<dim3(NS/16, NB), dim3(256), 0, stream>>>(U32(o_eo16), F(o_WeT), b_attn,
        (unsigned short*)(ws+o_eppk));

    k_dec<<<dim3(NB*G), dim3(1024), 0, stream>>>(U32(o_eo16), U32(o_eppk),
        U32(o_WhT16), v, F(o_zc), F(o_wy), U32(o_WdTg), dec_c0, W_lin, b_lin,
        F(o_hG), F(o_yG), F(o_ctxG), F(o_msG), (unsigned*)(ws+o_ctr), out);
}